// Round 8
// baseline (265.672 us; speedup 1.0000x reference)
//
#include <hip/hip_runtime.h>
#include <hip/hip_bf16.h>

#define D 64
#define CLAMP_V -10000.0f
#define SBSHIFT 9           // super-bucket = 512 nodes (dst >> 9)
#define SBN 512
#define MAXSB 256           // static bound; runtime nbSB = ceil(100k/512) = 196
#define HCHUNK 4096         // edges per hist slice (inside prep)
#define SCHUNK 4096         // edges per scatter block
#define SLICE 64            // nodes per segmax block (8 slices / SB)
#define SEGW 4096           // segmax sweep window (entries of SB range)

typedef __bf16 bf16x4 __attribute__((ext_vector_type(4)));
typedef __bf16 bf16x8 __attribute__((ext_vector_type(8)));
typedef float floatx4 __attribute__((ext_vector_type(4)));
typedef unsigned short u16x2 __attribute__((ext_vector_type(2)));
typedef short s16x2 __attribute__((ext_vector_type(2)));

// packed max of 2x u16 (v_pk_max_u16)
__device__ __forceinline__ unsigned pkmax(unsigned a, unsigned b) {
    u16x2 r = __builtin_elementwise_max(__builtin_bit_cast(u16x2, a),
                                        __builtin_bit_cast(u16x2, b));
    return __builtin_bit_cast(unsigned, r);
}
// packed ord-encode of 2x bf16 (monotone u16): pos -> |0x8000, neg -> ~
__device__ __forceinline__ unsigned pk_ord_encode(unsigned g) {
    s16x2 t = __builtin_bit_cast(s16x2, g) >> 15;
    unsigned m = __builtin_bit_cast(unsigned, t) & 0x7FFF7FFFu;
    return g ^ (m | 0x80008000u);
}
__device__ __forceinline__ unsigned pk_ord_decode(unsigned e) {
    s16x2 t = __builtin_bit_cast(s16x2, e) >> 15;
    unsigned m = (~__builtin_bit_cast(unsigned, t)) & 0x7FFF7FFFu;
    return e ^ (m | 0x80008000u);
}

// ---------- pass 0: fp32->bf16 conversion + SB histogram + W frag layout ---
__global__ __launch_bounds__(256) void prep_kernel(
        const float* __restrict__ nf, __bf16* __restrict__ nf16, int n4,
        const int* __restrict__ dst, unsigned* __restrict__ ghist,
        int nE, int nbSB,
        const float* __restrict__ W, __bf16* __restrict__ wfrag,
        int histBlocks, int wBlock) {
    __shared__ unsigned h[MAXSB];
    int blk = blockIdx.x, t = threadIdx.x;
    int i = blk * 256 + t;
    if (i < n4) {
        float4 v = ((const float4*)nf)[i];
        bf16x4 o = { (__bf16)v.x, (__bf16)v.y, (__bf16)v.z, (__bf16)v.w };
        ((bf16x4*)nf16)[i] = o;
    }
    if (blk < histBlocks) {
        if (t < MAXSB) h[t] = 0;
        __syncthreads();
        int e0 = blk * HCHUNK;
        int ec = nE - e0; if (ec > HCHUNK) ec = HCHUNK;
        for (int k = t; k < ec; k += 256) atomicAdd(&h[dst[e0 + k] >> SBSHIFT], 1u);
        __syncthreads();
        if (t < (unsigned)nbSB && h[t]) atomicAdd(&ghist[t], h[t]);
    }
    if (blk == wBlock) {
        // W[k][n] fp32 -> bf16 in MFMA-fragment order:
        // fidx = ((ks*4+c)*64 + quad*16+l16)*8 + j, k=ks*32+quad*8+j, n=c*16+l16
        for (int idx = t; idx < 2 * D * D; idx += 256) {
            int k = idx >> 6, n = idx & 63;
            int ks = k >> 5, r = k & 31, quad = r >> 3, j = r & 7;
            int c = n >> 4, l16 = n & 15;
            int fidx = (((ks * 4 + c) * 64) + quad * 16 + l16) * 8 + j;
            wfrag[fidx] = (__bf16)W[idx];
        }
    }
}

// ---------- pass B: exclusive scan over nbSB (single block) ----------
__global__ __launch_bounds__(256) void scan_sb(
        const unsigned* __restrict__ ghist, unsigned* __restrict__ base,
        unsigned* __restrict__ cursor, int nbSB) {
    __shared__ unsigned ts[256];
    int t = threadIdx.x;
    unsigned v = (t < nbSB) ? ghist[t] : 0u;
    ts[t] = v; __syncthreads();
    for (int off = 1; off < 256; off <<= 1) {
        unsigned x = (t >= off) ? ts[t - off] : 0u;
        __syncthreads();
        ts[t] += x;
        __syncthreads();
    }
    if (t < nbSB) {
        unsigned ex = ts[t] - v;
        base[t] = ex; cursor[t] = ex;
        if (t == nbSB - 1) base[nbSB] = ts[t];
    }
}

// ---------- pass C: bin edges into 196 super-buckets, coalesced flush ------
// entry = (dst&511)<<17 | src  (src < 2^17)
__global__ __launch_bounds__(256) void sb_scatter(
        const int* __restrict__ src, const int* __restrict__ dst,
        unsigned* __restrict__ cursor, unsigned* __restrict__ packed,
        int nE, int nbSB) {
    __shared__ unsigned cop[MAXSB];            // cnt low16, off high16
    __shared__ unsigned short lb16[MAXSB];
    __shared__ unsigned gbase[MAXSB];
    __shared__ unsigned payload[SCHUNK];       // 16 KB, bucket-sorted entries
    __shared__ unsigned char sbid[SCHUNK];     // 4 KB
    __shared__ unsigned ts[256];
    int t = threadIdx.x;
    int e0 = blockIdx.x * SCHUNK;
    int ec = nE - e0; if (ec > SCHUNK) ec = SCHUNK;

    if (t < MAXSB) cop[t] = 0;
    __syncthreads();
    for (int i = t; i < ec; i += 256)
        atomicAdd(&cop[dst[e0 + i] >> SBSHIFT], 1u);
    __syncthreads();
    unsigned c = (t < nbSB) ? (cop[t] & 0xFFFFu) : 0u;
    ts[t] = c; __syncthreads();
    for (int o = 1; o < 256; o <<= 1) {
        unsigned x = (t >= o) ? ts[t - o] : 0u;
        __syncthreads();
        ts[t] += x;
        __syncthreads();
    }
    if (t < nbSB) {
        lb16[t] = (unsigned short)(ts[t] - c);
        if (c) gbase[t] = atomicAdd(&cursor[t], c);
    }
    __syncthreads();
    for (int i = t; i < ec; i += 256) {
        int e = e0 + i;
        int d = dst[e];
        int b = d >> SBSHIFT;
        unsigned p = atomicAdd(&cop[b], 0x10000u) >> 16;
        unsigned pos = (unsigned)lb16[b] + p;
        payload[pos] = ((unsigned)(d & (SBN - 1)) << 17) | (unsigned)src[e];
        sbid[pos] = (unsigned char)b;
    }
    __syncthreads();
    // flush: payload is bucket-sorted; same-bucket entries are adjacent ->
    // runs of ~21 entries -> line-coalesced bursts
    for (int i = t; i < ec; i += 256) {
        unsigned b = sbid[i];
        packed[gbase[b] + ((unsigned)i - (unsigned)lb16[b])] = payload[i];
    }
}

// ---------- pass D: slice segmax. block = 64-node slice of a super-bucket --
__global__ __launch_bounds__(256) void seg_slice(
        const unsigned* __restrict__ nfu,       // nf16 as dwords, 32/row
        const unsigned* __restrict__ packed,
        const unsigned* __restrict__ base,
        unsigned* __restrict__ agg16u,          // bf16 agg as dwords, 32/row
        int nN) {
    __shared__ unsigned aggS[SLICE * 32];       // 8 KB packed ord-bf16 max
    __shared__ unsigned sbuf[SEGW];             // 16 KB slice src indices
    __shared__ unsigned rstart[SLICE + 1];
    __shared__ unsigned pos[SLICE];
    int blk = blockIdx.x;
    int sb = blk >> 3, slice = blk & 7;
    int n0 = sb * SBN + slice * SLICE;
    if (n0 >= nN) return;                        // empty tail slice
    int t = threadIdx.x;
    int wv = t >> 6, ln = t & 63;
    int half = ln >> 5, dln = ln & 31;

    for (int i = t; i < SLICE * 32; i += 256) aggS[i] = 0;  // minimal ord
    unsigned beg = base[sb], end = base[sb + 1];

    for (unsigned s0 = beg; s0 < end; s0 += SEGW) {
        unsigned scnt = end - s0; if (scnt > SEGW) scnt = SEGW;
        if (t < SLICE) pos[t] = 0;
        __syncthreads();
        // count our slice's entries in this window
        for (unsigned i = t; i < scnt; i += 256) {
            unsigned dL = packed[s0 + i] >> 17;          // 9 bits
            if ((int)(dL >> 6) == slice) atomicAdd(&pos[dL & 63], 1u);
        }
        __syncthreads();
        // wave 0: shfl exclusive scan of 64 bins
        if (t < 64) {
            unsigned vv = pos[t];
            unsigned x = vv;
            #pragma unroll
            for (int o = 1; o < 64; o <<= 1) {
                unsigned y = __shfl_up(x, o, 64);
                if (t >= o) x += y;
            }
            rstart[t] = x - vv;
            pos[t] = x - vv;
            if (t == 63) rstart[64] = x;
        }
        __syncthreads();
        // sort slice entries into sbuf
        for (unsigned i = t; i < scnt; i += 256) {
            unsigned e = packed[s0 + i];
            unsigned dL = e >> 17;
            if ((int)(dL >> 6) == slice) {
                unsigned p = atomicAdd(&pos[dL & 63], 1u);
                sbuf[p] = e & 0x1FFFFu;
            }
        }
        __syncthreads();
        // register max over contiguous runs; 2 edges/iter per accumulator,
        // unroll x2 (4 edges in flight), 2 dims/lane packed
        for (int node = wv; node < SLICE; node += 4) {
            unsigned rb = rstart[node], re = rstart[node + 1];
            if (rb == re) continue;
            unsigned m0 = 0, m1 = 0;
            unsigned j = rb;
            for (; j + 4 <= re; j += 4) {
                unsigned sa  = sbuf[j + half];
                unsigned sb2 = sbuf[j + 2 + half];
                unsigned g0 = nfu[(size_t)sa * 32 + dln];
                unsigned g1 = nfu[(size_t)sb2 * 32 + dln];
                m0 = pkmax(m0, pk_ord_encode(g0));
                m1 = pkmax(m1, pk_ord_encode(g1));
            }
            for (; j < re; j += 2) {
                unsigned jj = j + (unsigned)half;
                if (jj < re) {
                    unsigned g = nfu[(size_t)sbuf[jj] * 32 + dln];
                    m0 = pkmax(m0, pk_ord_encode(g));
                }
            }
            unsigned m = pkmax(m0, m1);
            m = pkmax(m, __shfl_xor(m, 32, 64));    // cross-half merge
            if (ln < 32) {
                unsigned idx = node * 32 + ln;
                aggS[idx] = pkmax(aggS[idx], m);    // wave owns node
            }
        }
        __syncthreads();
    }
    // epilogue: decode, r = max(v) - x, clamp, store bf16 pair
    for (int node = wv; node < SLICE; node += 4) {
        int n = n0 + node;
        if (n < nN && ln < 32) {
            unsigned raw = pk_ord_decode(aggS[node * 32 + ln]); // empty -> NaN
            unsigned xr  = nfu[(size_t)n * 32 + ln];
            float v0 = __uint_as_float(raw << 16);
            float v1 = __uint_as_float(raw & 0xFFFF0000u);
            float x0 = __uint_as_float(xr << 16);
            float x1 = __uint_as_float(xr & 0xFFFF0000u);
            float r0 = v0 - x0; r0 = (r0 >= CLAMP_V) ? r0 : 0.0f;  // NaN -> 0
            float r1 = v1 - x1; r1 = (r1 >= CLAMP_V) ? r1 : 0.0f;
            __bf16 b0 = (__bf16)r0, b1 = (__bf16)r1;
            unsigned o = ((unsigned)__builtin_bit_cast(unsigned short, b1) << 16)
                       |  (unsigned)__builtin_bit_cast(unsigned short, b0);
            agg16u[(size_t)n * 32 + ln] = o;
        }
    }
}

// ---------- pass E: MFMA MLP; W from frag-order buffer ----------
__global__ __launch_bounds__(256) void node_mlp_mfma(
        const __bf16* __restrict__ nf16,
        const __bf16* __restrict__ agg16,
        float* __restrict__ out,
        const __bf16* __restrict__ wfrag,
        const float* __restrict__ bias,
        int nTiles, int nN) {
    int lane = threadIdx.x & 63;
    int quad = lane >> 4;
    int l16  = lane & 15;
    int waveGlobal = blockIdx.x * 4 + (threadIdx.x >> 6);
    int nWaves = gridDim.x * 4;

    bf16x8 bfrag[4][4];
    #pragma unroll
    for (int c = 0; c < 4; ++c)
        #pragma unroll
        for (int ks = 0; ks < 4; ++ks)
            bfrag[c][ks] = *(const bf16x8*)(wfrag + ((size_t)((ks * 4 + c) * 64 + lane)) * 8);
    float bv[4];
    #pragma unroll
    for (int c = 0; c < 4; ++c) bv[c] = bias[c * 16 + l16];

    for (int t = waveGlobal; t < nTiles; t += nWaves) {
        int n0 = t * 16;
        int rowA = n0 + l16;
        if (rowA >= nN) rowA = nN - 1;
        const __bf16* nfr = nf16  + (size_t)rowA * D;
        const __bf16* agr = agg16 + (size_t)rowA * D;

        floatx4 acc[4] = {{0,0,0,0},{0,0,0,0},{0,0,0,0},{0,0,0,0}};
        #pragma unroll
        for (int ks = 0; ks < 4; ++ks) {
            const __bf16* p = (ks < 2) ? (nfr + ks * 32 + quad * 8)
                                       : (agr + (ks - 2) * 32 + quad * 8);
            bf16x8 a = *(const bf16x8*)p;
            #pragma unroll
            for (int c = 0; c < 4; ++c)
                acc[c] = __builtin_amdgcn_mfma_f32_16x16x32_bf16(
                             a, bfrag[c][ks], acc[c], 0, 0, 0);
        }
        #pragma unroll
        for (int r = 0; r < 4; ++r) {
            int row = n0 + quad * 4 + r;
            if (row < nN) {
                #pragma unroll
                for (int c = 0; c < 4; ++c) {
                    float vv = acc[c][r] + bv[c];
                    out[(size_t)row * D + c * 16 + l16] = fmaxf(vv, 0.0f);
                }
            }
        }
    }
}

extern "C" void kernel_launch(void* const* d_in, const int* in_sizes, int n_in,
                              void* d_out, int out_size, void* d_ws, size_t ws_size,
                              hipStream_t stream) {
    const float* nf  = (const float*)d_in[0];
    const int*   src = (const int*)d_in[1];
    const int*   dst = (const int*)d_in[2];
    const float* W   = (const float*)d_in[3];
    const float* b   = (const float*)d_in[4];
    float* out = (float*)d_out;

    int nN = in_sizes[0] / D;
    int nE = in_sizes[1];
    int nbSB = (nN + SBN - 1) / SBN;            // 196

    // ws layout
    char* wsb = (char*)d_ws;
    size_t nfB  = (((size_t)nN * D * 2) + 255) & ~(size_t)255;  // 12.8 MB
    size_t pkB  = (((size_t)nE * 4)     + 255) & ~(size_t)255;  // 6.4 MB
    __bf16*   nf16   = (__bf16*)wsb;
    __bf16*   agg16  = (__bf16*)(wsb + nfB);
    unsigned* packed = (unsigned*)(wsb + 2 * nfB);
    unsigned* ghist  = (unsigned*)(wsb + 2 * nfB + pkB);
    unsigned* base   = (unsigned*)(wsb + 2 * nfB + pkB + 4 * MAXSB);
    unsigned* cursor = (unsigned*)(wsb + 2 * nfB + pkB + 4 * MAXSB + 4 * (MAXSB + 2));
    __bf16*   wfrag  = (__bf16*)(wsb + 2 * nfB + pkB + 4 * MAXSB + 8 * (MAXSB + 2));

    hipMemsetAsync(ghist, 0, (size_t)nbSB * 4, stream);

    int n4 = nN * D / 4;                        // 1.6M
    int convBlocks = (n4 + 255) / 256;          // 6250
    int histBlocks = (nE + HCHUNK - 1) / HCHUNK;// 391
    int gridPrep = convBlocks > histBlocks ? convBlocks : histBlocks;
    prep_kernel<<<gridPrep, 256, 0, stream>>>(nf, nf16, n4, dst, ghist, nE, nbSB,
                                              W, wfrag, histBlocks, gridPrep - 1);

    scan_sb<<<1, 256, 0, stream>>>(ghist, base, cursor, nbSB);

    int nbS = (nE + SCHUNK - 1) / SCHUNK;       // 391
    sb_scatter<<<nbS, 256, 0, stream>>>(src, dst, cursor, packed, nE, nbSB);

    seg_slice<<<nbSB * 8, 256, 0, stream>>>((const unsigned*)nf16, packed, base,
                                            (unsigned*)agg16, nN);

    int nTiles = (nN + 15) / 16;
    node_mlp_mfma<<<768, 256, 0, stream>>>(nf16, agg16, out, wfrag, b, nTiles, nN);
}

// Round 10
// 255.200 us; speedup vs baseline: 1.0410x; 1.0410x over previous
//
#include <hip/hip_runtime.h>
#include <hip/hip_bf16.h>

#define D 64
#define CLAMP_V -10000.0f
#define SBSHIFT 9           // super-bucket = 512 nodes (dst >> 9)
#define SBN 512
#define MAXSB 256           // static bound; runtime nbSB = ceil(100k/512) = 196
#define HCHUNK 4096         // edges per hist slice (inside prep)
#define SCHUNK 4096         // edges per scatter block

typedef __bf16 bf16x4 __attribute__((ext_vector_type(4)));
typedef __bf16 bf16x8 __attribute__((ext_vector_type(8)));
typedef float floatx4 __attribute__((ext_vector_type(4)));
typedef unsigned short u16x2 __attribute__((ext_vector_type(2)));
typedef short s16x2 __attribute__((ext_vector_type(2)));

// packed max of 2x u16 (v_pk_max_u16)
__device__ __forceinline__ unsigned pkmax(unsigned a, unsigned b) {
    u16x2 r = __builtin_elementwise_max(__builtin_bit_cast(u16x2, a),
                                        __builtin_bit_cast(u16x2, b));
    return __builtin_bit_cast(unsigned, r);
}
// packed ord-encode of 2x bf16 (monotone u16): pos -> |0x8000, neg -> ~
__device__ __forceinline__ unsigned pk_ord_encode(unsigned g) {
    s16x2 t = __builtin_bit_cast(s16x2, g) >> 15;
    unsigned m = __builtin_bit_cast(unsigned, t) & 0x7FFF7FFFu;
    return g ^ (m | 0x80008000u);
}
__device__ __forceinline__ unsigned pk_ord_decode(unsigned e) {
    s16x2 t = __builtin_bit_cast(s16x2, e) >> 15;
    unsigned m = (~__builtin_bit_cast(unsigned, t)) & 0x7FFF7FFFu;
    return e ^ (m | 0x80008000u);
}

// ---------- pass 0: fp32->bf16 conversion + SB histogram + W frag layout ---
__global__ __launch_bounds__(256) void prep_kernel(
        const float* __restrict__ nf, __bf16* __restrict__ nf16, int n4,
        const int* __restrict__ dst, unsigned* __restrict__ ghist,
        int nE, int nbSB,
        const float* __restrict__ W, __bf16* __restrict__ wfrag,
        int histBlocks, int wBlock) {
    __shared__ unsigned h[MAXSB];
    int blk = blockIdx.x, t = threadIdx.x;
    int i = blk * 256 + t;
    if (i < n4) {
        float4 v = ((const float4*)nf)[i];
        bf16x4 o = { (__bf16)v.x, (__bf16)v.y, (__bf16)v.z, (__bf16)v.w };
        ((bf16x4*)nf16)[i] = o;
    }
    if (blk < histBlocks) {
        if (t < MAXSB) h[t] = 0;
        __syncthreads();
        int e0 = blk * HCHUNK;
        int ec = nE - e0; if (ec > HCHUNK) ec = HCHUNK;
        for (int k = t; k < ec; k += 256) atomicAdd(&h[dst[e0 + k] >> SBSHIFT], 1u);
        __syncthreads();
        if (t < (unsigned)nbSB && h[t]) atomicAdd(&ghist[t], h[t]);
    }
    if (blk == wBlock) {
        // W[k][n] fp32 -> bf16 in MFMA-fragment order:
        // fidx = ((ks*4+c)*64 + quad*16+l16)*8 + j, k=ks*32+quad*8+j, n=c*16+l16
        for (int idx = t; idx < 2 * D * D; idx += 256) {
            int k = idx >> 6, n = idx & 63;
            int ks = k >> 5, r = k & 31, quad = r >> 3, j = r & 7;
            int c = n >> 4, l16 = n & 15;
            int fidx = (((ks * 4 + c) * 64) + quad * 16 + l16) * 8 + j;
            wfrag[fidx] = (__bf16)W[idx];
        }
    }
}

// ---------- pass B: exclusive scan over nbSB (single block) ----------
__global__ __launch_bounds__(256) void scan_sb(
        const unsigned* __restrict__ ghist, unsigned* __restrict__ base,
        unsigned* __restrict__ cursor, int nbSB) {
    __shared__ unsigned ts[256];
    int t = threadIdx.x;
    unsigned v = (t < nbSB) ? ghist[t] : 0u;
    ts[t] = v; __syncthreads();
    for (int off = 1; off < 256; off <<= 1) {
        unsigned x = (t >= off) ? ts[t - off] : 0u;
        __syncthreads();
        ts[t] += x;
        __syncthreads();
    }
    if (t < nbSB) {
        unsigned ex = ts[t] - v;
        base[t] = ex; cursor[t] = ex;
        if (t == nbSB - 1) base[nbSB] = ts[t];
    }
}

// ---------- pass C: bin edges into 196 super-buckets, coalesced flush ------
// entry = (dst&511)<<17 | src  (src < 2^17)
__global__ __launch_bounds__(256) void sb_scatter(
        const int* __restrict__ src, const int* __restrict__ dst,
        unsigned* __restrict__ cursor, unsigned* __restrict__ packed,
        int nE, int nbSB) {
    __shared__ unsigned cop[MAXSB];            // cnt low16, off high16
    __shared__ unsigned short lb16[MAXSB];
    __shared__ unsigned gbase[MAXSB];
    __shared__ unsigned payload[SCHUNK];       // 16 KB, bucket-sorted entries
    __shared__ unsigned char sbid[SCHUNK];     // 4 KB
    __shared__ unsigned ts[256];
    int t = threadIdx.x;
    int e0 = blockIdx.x * SCHUNK;
    int ec = nE - e0; if (ec > SCHUNK) ec = SCHUNK;

    if (t < MAXSB) cop[t] = 0;
    __syncthreads();
    for (int i = t; i < ec; i += 256)
        atomicAdd(&cop[dst[e0 + i] >> SBSHIFT], 1u);
    __syncthreads();
    unsigned c = (t < nbSB) ? (cop[t] & 0xFFFFu) : 0u;
    ts[t] = c; __syncthreads();
    for (int o = 1; o < 256; o <<= 1) {
        unsigned x = (t >= o) ? ts[t - o] : 0u;
        __syncthreads();
        ts[t] += x;
        __syncthreads();
    }
    if (t < nbSB) {
        lb16[t] = (unsigned short)(ts[t] - c);
        if (c) gbase[t] = atomicAdd(&cursor[t], c);
    }
    __syncthreads();
    for (int i = t; i < ec; i += 256) {
        int e = e0 + i;
        int d = dst[e];
        int b = d >> SBSHIFT;
        unsigned p = atomicAdd(&cop[b], 0x10000u) >> 16;
        unsigned pos = (unsigned)lb16[b] + p;
        payload[pos] = ((unsigned)(d & (SBN - 1)) << 17) | (unsigned)src[e];
        sbid[pos] = (unsigned char)b;
    }
    __syncthreads();
    // flush: payload is bucket-sorted; same-bucket entries are adjacent ->
    // runs of ~21 entries -> line-coalesced bursts
    for (int i = t; i < ec; i += 256) {
        unsigned b = sbid[i];
        packed[gbase[b] + ((unsigned)i - (unsigned)lb16[b])] = payload[i];
    }
}

// ---------- pass C2: per-SB counting sort to node order + CSR nodestart ----
__global__ __launch_bounds__(256) void sb_sort(
        const unsigned* __restrict__ packed1, const unsigned* __restrict__ base,
        unsigned* __restrict__ packed2, unsigned* __restrict__ nodestart,
        int nN) {
    __shared__ unsigned cnt[SBN];               // 2 KB
    __shared__ unsigned ts[256];
    int sb = blockIdx.x, t = threadIdx.x;
    unsigned beg = base[sb], end = base[sb + 1];
    cnt[2 * t] = 0; cnt[2 * t + 1] = 0;
    __syncthreads();
    for (unsigned i = beg + t; i < end; i += 256)
        atomicAdd(&cnt[packed1[i] >> 17], 1u);
    __syncthreads();
    unsigned a = cnt[2 * t], b = cnt[2 * t + 1], s = a + b;
    ts[t] = s; __syncthreads();
    for (int o = 1; o < 256; o <<= 1) {
        unsigned x = (t >= o) ? ts[t - o] : 0u;
        __syncthreads();
        ts[t] += x;
        __syncthreads();
    }
    unsigned ex = ts[t] - s;
    // each thread owns bins 2t,2t+1: safe to overwrite with cursors
    cnt[2 * t] = ex; cnt[2 * t + 1] = ex + a;
    int n0 = sb * SBN;
    if (n0 + 2 * t     <= nN) nodestart[n0 + 2 * t]     = beg + ex;
    if (n0 + 2 * t + 1 <= nN) nodestart[n0 + 2 * t + 1] = beg + ex + a;
    __syncthreads();
    // scatter to node-sorted order (writes confined to hot 32 KB window)
    for (unsigned i = beg + t; i < end; i += 256) {
        unsigned e = packed1[i];
        unsigned p = atomicAdd(&cnt[e >> 17], 1u);
        packed2[beg + p] = e & 0x1FFFFu;        // src only; position encodes node
    }
}

// ---------- pass D: direct segmax over CSR runs; zero LDS ----------
// wave owns 32 consecutive nodes; per node: coalesced run prefetch +
// shfl-broadcast, 2 edges/iter, 2 packed dims/lane register max.
// NOTE: every __shfl below must execute with ALL 64 lanes active —
// ds_bpermute data from exec-masked source lanes is undefined (R9 bug:
// divergent `if (jj < lim)` tail corrupted odd-remainder runs). Tails are
// handled by clamping the index (dup edge; max is idempotent).
__global__ __launch_bounds__(256) void seg_direct(
        const unsigned* __restrict__ nfu,       // nf16 as dwords, 32/row
        const unsigned* __restrict__ packed2,   // node-sorted src indices
        const unsigned* __restrict__ nodestart,
        unsigned* __restrict__ agg16u,          // bf16 agg as dwords, 32/row
        int nN) {
    int t = threadIdx.x;
    int wv = t >> 6, ln = t & 63;
    int half = ln >> 5, dln = ln & 31;
    int n0 = blockIdx.x * 128 + wv * 32;
    #pragma unroll 1
    for (int k = 0; k < 32; ++k) {
        int n = n0 + k;
        if (n >= nN) break;
        unsigned rb = nodestart[n], re = nodestart[n + 1];
        unsigned m0 = 0, m1 = 0;
        for (unsigned c = rb; c < re; c += 64) {
            unsigned idx = c + (unsigned)ln;
            unsigned pe = (idx < re) ? packed2[idx] : 0u;
            int lim = (int)(re - c); if (lim > 64) lim = 64;
            int j = 0;
            for (; j + 4 <= lim; j += 4) {
                unsigned sa  = __shfl(pe, j + half, 64);
                unsigned sb2 = __shfl(pe, j + 2 + half, 64);
                unsigned g0 = nfu[(size_t)sa * 32 + dln];
                unsigned g1 = nfu[(size_t)sb2 * 32 + dln];
                m0 = pkmax(m0, pk_ord_encode(g0));
                m1 = pkmax(m1, pk_ord_encode(g1));
            }
            for (; j < lim; j += 2) {
                int jj = j + half;
                if (jj >= lim) jj = lim - 1;    // dup tail: max idempotent,
                                                // keeps wave convergent for shfl
                unsigned g = nfu[(size_t)__shfl(pe, jj, 64) * 32 + dln];
                m0 = pkmax(m0, pk_ord_encode(g));
            }
        }
        unsigned m = pkmax(m0, m1);
        m = pkmax(m, __shfl_xor(m, 32, 64));    // cross-half merge
        if (ln < 32) {
            unsigned raw = pk_ord_decode(m);    // empty run -> NaN halves
            unsigned xr  = nfu[(size_t)n * 32 + dln];
            float v0 = __uint_as_float(raw << 16);
            float v1 = __uint_as_float(raw & 0xFFFF0000u);
            float x0 = __uint_as_float(xr << 16);
            float x1 = __uint_as_float(xr & 0xFFFF0000u);
            float r0 = v0 - x0; r0 = (r0 >= CLAMP_V) ? r0 : 0.0f;  // NaN -> 0
            float r1 = v1 - x1; r1 = (r1 >= CLAMP_V) ? r1 : 0.0f;
            __bf16 b0 = (__bf16)r0, b1 = (__bf16)r1;
            unsigned o = ((unsigned)__builtin_bit_cast(unsigned short, b1) << 16)
                       |  (unsigned)__builtin_bit_cast(unsigned short, b0);
            agg16u[(size_t)n * 32 + dln] = o;
        }
    }
}

// ---------- pass E: MFMA MLP; W from frag-order buffer ----------
__global__ __launch_bounds__(256) void node_mlp_mfma(
        const __bf16* __restrict__ nf16,
        const __bf16* __restrict__ agg16,
        float* __restrict__ out,
        const __bf16* __restrict__ wfrag,
        const float* __restrict__ bias,
        int nTiles, int nN) {
    int lane = threadIdx.x & 63;
    int quad = lane >> 4;
    int l16  = lane & 15;
    int waveGlobal = blockIdx.x * 4 + (threadIdx.x >> 6);
    int nWaves = gridDim.x * 4;

    bf16x8 bfrag[4][4];
    #pragma unroll
    for (int c = 0; c < 4; ++c)
        #pragma unroll
        for (int ks = 0; ks < 4; ++ks)
            bfrag[c][ks] = *(const bf16x8*)(wfrag + ((size_t)((ks * 4 + c) * 64 + lane)) * 8);
    float bv[4];
    #pragma unroll
    for (int c = 0; c < 4; ++c) bv[c] = bias[c * 16 + l16];

    for (int t = waveGlobal; t < nTiles; t += nWaves) {
        int n0 = t * 16;
        int rowA = n0 + l16;
        if (rowA >= nN) rowA = nN - 1;
        const __bf16* nfr = nf16  + (size_t)rowA * D;
        const __bf16* agr = agg16 + (size_t)rowA * D;

        floatx4 acc[4] = {{0,0,0,0},{0,0,0,0},{0,0,0,0},{0,0,0,0}};
        #pragma unroll
        for (int ks = 0; ks < 4; ++ks) {
            const __bf16* p = (ks < 2) ? (nfr + ks * 32 + quad * 8)
                                       : (agr + (ks - 2) * 32 + quad * 8);
            bf16x8 a = *(const bf16x8*)p;
            #pragma unroll
            for (int c = 0; c < 4; ++c)
                acc[c] = __builtin_amdgcn_mfma_f32_16x16x32_bf16(
                             a, bfrag[c][ks], acc[c], 0, 0, 0);
        }
        #pragma unroll
        for (int r = 0; r < 4; ++r) {
            int row = n0 + quad * 4 + r;
            if (row < nN) {
                #pragma unroll
                for (int c = 0; c < 4; ++c) {
                    float vv = acc[c][r] + bv[c];
                    out[(size_t)row * D + c * 16 + l16] = fmaxf(vv, 0.0f);
                }
            }
        }
    }
}

extern "C" void kernel_launch(void* const* d_in, const int* in_sizes, int n_in,
                              void* d_out, int out_size, void* d_ws, size_t ws_size,
                              hipStream_t stream) {
    const float* nf  = (const float*)d_in[0];
    const int*   src = (const int*)d_in[1];
    const int*   dst = (const int*)d_in[2];
    const float* W   = (const float*)d_in[3];
    const float* b   = (const float*)d_in[4];
    float* out = (float*)d_out;

    int nN = in_sizes[0] / D;
    int nE = in_sizes[1];
    int nbSB = (nN + SBN - 1) / SBN;            // 196

    // ws layout
    char* wsb = (char*)d_ws;
    size_t nfB  = (((size_t)nN * D * 2) + 255) & ~(size_t)255;  // 12.8 MB
    size_t pkB  = (((size_t)nE * 4)     + 255) & ~(size_t)255;  // 6.4 MB
    __bf16*   nf16   = (__bf16*)wsb;
    __bf16*   agg16  = (__bf16*)(wsb + nfB);
    unsigned* packed1 = (unsigned*)(wsb + 2 * nfB);
    unsigned* ghist  = (unsigned*)(wsb + 2 * nfB + pkB);
    unsigned* base   = (unsigned*)(wsb + 2 * nfB + pkB + 4 * MAXSB);
    unsigned* cursor = (unsigned*)(wsb + 2 * nfB + pkB + 4 * MAXSB + 4 * (MAXSB + 2));
    __bf16*   wfrag  = (__bf16*)(wsb + 2 * nfB + pkB + 4 * MAXSB + 8 * (MAXSB + 2));
    unsigned* nodestart = (unsigned*)(wsb + 2 * nfB + pkB + 4 * MAXSB
                                      + 8 * (MAXSB + 2) + 32768);
    // packed2 lives in d_out: consumed by seg_direct before the MLP writes out
    unsigned* packed2 = (unsigned*)d_out;

    hipMemsetAsync(ghist, 0, (size_t)nbSB * 4, stream);

    int n4 = nN * D / 4;                        // 1.6M
    int convBlocks = (n4 + 255) / 256;          // 6250
    int histBlocks = (nE + HCHUNK - 1) / HCHUNK;// 391
    int gridPrep = convBlocks > histBlocks ? convBlocks : histBlocks;
    prep_kernel<<<gridPrep, 256, 0, stream>>>(nf, nf16, n4, dst, ghist, nE, nbSB,
                                              W, wfrag, histBlocks, gridPrep - 1);

    scan_sb<<<1, 256, 0, stream>>>(ghist, base, cursor, nbSB);

    int nbS = (nE + SCHUNK - 1) / SCHUNK;       // 391
    sb_scatter<<<nbS, 256, 0, stream>>>(src, dst, cursor, packed1, nE, nbSB);

    sb_sort<<<nbSB, 256, 0, stream>>>(packed1, base, packed2, nodestart, nN);

    seg_direct<<<(nN + 127) / 128, 256, 0, stream>>>(
        (const unsigned*)nf16, packed2, nodestart, (unsigned*)agg16, nN);

    int nTiles = (nN + 15) / 16;
    node_mlp_mfma<<<768, 256, 0, stream>>>(nf16, agg16, out, wfrag, b, nTiles, nN);
}

// Round 11
// 200.736 us; speedup vs baseline: 1.3235x; 1.2713x over previous
//
#include <hip/hip_runtime.h>
#include <hip/hip_bf16.h>

#define D 64
#define CLAMP_V -10000.0f
#define SBSHIFT 9           // super-bucket = 512 nodes (dst >> 9)
#define SBN 512
#define MAXSB 256           // static bound; runtime nbSB = ceil(100k/512) = 196
#define HCHUNK 4096         // edges per hist slice (inside prep)
#define SCHUNK 4096         // edges per scatter block
#define NPW 8               // nodes per wave in seg_direct (grid = nN/32 blocks)

typedef __bf16 bf16x4 __attribute__((ext_vector_type(4)));
typedef __bf16 bf16x8 __attribute__((ext_vector_type(8)));
typedef float floatx4 __attribute__((ext_vector_type(4)));
typedef unsigned short u16x2 __attribute__((ext_vector_type(2)));
typedef short s16x2 __attribute__((ext_vector_type(2)));

// packed max of 2x u16 (v_pk_max_u16)
__device__ __forceinline__ unsigned pkmax(unsigned a, unsigned b) {
    u16x2 r = __builtin_elementwise_max(__builtin_bit_cast(u16x2, a),
                                        __builtin_bit_cast(u16x2, b));
    return __builtin_bit_cast(unsigned, r);
}
// packed ord-encode of 2x bf16 (monotone u16): pos -> |0x8000, neg -> ~
__device__ __forceinline__ unsigned pk_ord_encode(unsigned g) {
    s16x2 t = __builtin_bit_cast(s16x2, g) >> 15;
    unsigned m = __builtin_bit_cast(unsigned, t) & 0x7FFF7FFFu;
    return g ^ (m | 0x80008000u);
}
__device__ __forceinline__ unsigned pk_ord_decode(unsigned e) {
    s16x2 t = __builtin_bit_cast(s16x2, e) >> 15;
    unsigned m = (~__builtin_bit_cast(unsigned, t)) & 0x7FFF7FFFu;
    return e ^ (m | 0x80008000u);
}

// ---------- pass 0: fp32->bf16 conversion + SB histogram + W frag layout ---
__global__ __launch_bounds__(256) void prep_kernel(
        const float* __restrict__ nf, __bf16* __restrict__ nf16, int n4,
        const int* __restrict__ dst, unsigned* __restrict__ ghist,
        int nE, int nbSB,
        const float* __restrict__ W, __bf16* __restrict__ wfrag,
        int histBlocks, int wBlock) {
    __shared__ unsigned h[MAXSB];
    int blk = blockIdx.x, t = threadIdx.x;
    int i = blk * 256 + t;
    if (i < n4) {
        float4 v = ((const float4*)nf)[i];
        bf16x4 o = { (__bf16)v.x, (__bf16)v.y, (__bf16)v.z, (__bf16)v.w };
        ((bf16x4*)nf16)[i] = o;
    }
    if (blk < histBlocks) {
        if (t < MAXSB) h[t] = 0;
        __syncthreads();
        int e0 = blk * HCHUNK;
        int ec = nE - e0; if (ec > HCHUNK) ec = HCHUNK;
        for (int k = t; k < ec; k += 256) atomicAdd(&h[dst[e0 + k] >> SBSHIFT], 1u);
        __syncthreads();
        if (t < (unsigned)nbSB && h[t]) atomicAdd(&ghist[t], h[t]);
    }
    if (blk == wBlock) {
        // W[k][n] fp32 -> bf16 in MFMA-fragment order:
        // fidx = ((ks*4+c)*64 + quad*16+l16)*8 + j, k=ks*32+quad*8+j, n=c*16+l16
        for (int idx = t; idx < 2 * D * D; idx += 256) {
            int k = idx >> 6, n = idx & 63;
            int ks = k >> 5, r = k & 31, quad = r >> 3, j = r & 7;
            int c = n >> 4, l16 = n & 15;
            int fidx = (((ks * 4 + c) * 64) + quad * 16 + l16) * 8 + j;
            wfrag[fidx] = (__bf16)W[idx];
        }
    }
}

// ---------- pass B: exclusive scan over nbSB (single block) ----------
__global__ __launch_bounds__(256) void scan_sb(
        const unsigned* __restrict__ ghist, unsigned* __restrict__ base,
        unsigned* __restrict__ cursor, int nbSB) {
    __shared__ unsigned ts[256];
    int t = threadIdx.x;
    unsigned v = (t < nbSB) ? ghist[t] : 0u;
    ts[t] = v; __syncthreads();
    for (int off = 1; off < 256; off <<= 1) {
        unsigned x = (t >= off) ? ts[t - off] : 0u;
        __syncthreads();
        ts[t] += x;
        __syncthreads();
    }
    if (t < nbSB) {
        unsigned ex = ts[t] - v;
        base[t] = ex; cursor[t] = ex;
        if (t == nbSB - 1) base[nbSB] = ts[t];
    }
}

// ---------- pass C: bin edges into 196 super-buckets, coalesced flush ------
// entry = (dst&511)<<17 | src  (src < 2^17)
__global__ __launch_bounds__(256) void sb_scatter(
        const int* __restrict__ src, const int* __restrict__ dst,
        unsigned* __restrict__ cursor, unsigned* __restrict__ packed,
        int nE, int nbSB) {
    __shared__ unsigned cop[MAXSB];            // cnt low16, off high16
    __shared__ unsigned short lb16[MAXSB];
    __shared__ unsigned gbase[MAXSB];
    __shared__ unsigned payload[SCHUNK];       // 16 KB, bucket-sorted entries
    __shared__ unsigned char sbid[SCHUNK];     // 4 KB
    __shared__ unsigned ts[256];
    int t = threadIdx.x;
    int e0 = blockIdx.x * SCHUNK;
    int ec = nE - e0; if (ec > SCHUNK) ec = SCHUNK;

    if (t < MAXSB) cop[t] = 0;
    __syncthreads();
    for (int i = t; i < ec; i += 256)
        atomicAdd(&cop[dst[e0 + i] >> SBSHIFT], 1u);
    __syncthreads();
    unsigned c = (t < nbSB) ? (cop[t] & 0xFFFFu) : 0u;
    ts[t] = c; __syncthreads();
    for (int o = 1; o < 256; o <<= 1) {
        unsigned x = (t >= o) ? ts[t - o] : 0u;
        __syncthreads();
        ts[t] += x;
        __syncthreads();
    }
    if (t < nbSB) {
        lb16[t] = (unsigned short)(ts[t] - c);
        if (c) gbase[t] = atomicAdd(&cursor[t], c);
    }
    __syncthreads();
    for (int i = t; i < ec; i += 256) {
        int e = e0 + i;
        int d = dst[e];
        int b = d >> SBSHIFT;
        unsigned p = atomicAdd(&cop[b], 0x10000u) >> 16;
        unsigned pos = (unsigned)lb16[b] + p;
        payload[pos] = ((unsigned)(d & (SBN - 1)) << 17) | (unsigned)src[e];
        sbid[pos] = (unsigned char)b;
    }
    __syncthreads();
    // flush: payload is bucket-sorted; same-bucket entries are adjacent ->
    // runs of ~21 entries -> line-coalesced bursts
    for (int i = t; i < ec; i += 256) {
        unsigned b = sbid[i];
        packed[gbase[b] + ((unsigned)i - (unsigned)lb16[b])] = payload[i];
    }
}

// ---------- pass C2: per-SB counting sort to node order + CSR nodestart ----
__global__ __launch_bounds__(256) void sb_sort(
        const unsigned* __restrict__ packed1, const unsigned* __restrict__ base,
        unsigned* __restrict__ packed2, unsigned* __restrict__ nodestart,
        int nN) {
    __shared__ unsigned cnt[SBN];               // 2 KB
    __shared__ unsigned ts[256];
    int sb = blockIdx.x, t = threadIdx.x;
    unsigned beg = base[sb], end = base[sb + 1];
    cnt[2 * t] = 0; cnt[2 * t + 1] = 0;
    __syncthreads();
    for (unsigned i = beg + t; i < end; i += 256)
        atomicAdd(&cnt[packed1[i] >> 17], 1u);
    __syncthreads();
    unsigned a = cnt[2 * t], b = cnt[2 * t + 1], s = a + b;
    ts[t] = s; __syncthreads();
    for (int o = 1; o < 256; o <<= 1) {
        unsigned x = (t >= o) ? ts[t - o] : 0u;
        __syncthreads();
        ts[t] += x;
        __syncthreads();
    }
    unsigned ex = ts[t] - s;
    // each thread owns bins 2t,2t+1: safe to overwrite with cursors
    cnt[2 * t] = ex; cnt[2 * t + 1] = ex + a;
    int n0 = sb * SBN;
    if (n0 + 2 * t     <= nN) nodestart[n0 + 2 * t]     = beg + ex;
    if (n0 + 2 * t + 1 <= nN) nodestart[n0 + 2 * t + 1] = beg + ex + a;
    __syncthreads();
    // scatter to node-sorted order (writes confined to hot 32 KB window)
    for (unsigned i = beg + t; i < end; i += 256) {
        unsigned e = packed1[i];
        unsigned p = atomicAdd(&cnt[e >> 17], 1u);
        packed2[beg + p] = e & 0x1FFFFu;        // src only; position encodes node
    }
}

// ---------- pass D: direct segmax over CSR runs; zero LDS ----------
// wave owns NPW consecutive nodes; per node: coalesced run prefetch +
// shfl-broadcast, up to 8 edges/iter (4 gathers in flight), 2 packed
// dims/lane register max.
// NOTE: every __shfl must execute with ALL 64 lanes active — ds_bpermute
// data from exec-masked source lanes is undefined (R9 bug). Tails clamp
// the index (dup edge; max idempotent) to stay convergent.
__global__ __launch_bounds__(256) void seg_direct(
        const unsigned* __restrict__ nfu,       // nf16 as dwords, 32/row
        const unsigned* __restrict__ packed2,   // node-sorted src indices
        const unsigned* __restrict__ nodestart,
        unsigned* __restrict__ agg16u,          // bf16 agg as dwords, 32/row
        int nN) {
    int t = threadIdx.x;
    int wv = t >> 6, ln = t & 63;
    int half = ln >> 5, dln = ln & 31;
    int n0 = blockIdx.x * (4 * NPW) + wv * NPW;
    #pragma unroll 1
    for (int k = 0; k < NPW; ++k) {
        int n = n0 + k;                          // wave-uniform
        if (n >= nN) break;
        unsigned rb = nodestart[n], re = nodestart[n + 1];
        unsigned m0 = 0, m1 = 0, m2 = 0, m3 = 0;
        for (unsigned c = rb; c < re; c += 64) {
            unsigned idx = c + (unsigned)ln;
            unsigned pe = (idx < re) ? packed2[idx] : 0u;
            int lim = (int)(re - c); if (lim > 64) lim = 64;
            int j = 0;
            for (; j + 8 <= lim; j += 8) {
                unsigned sa = __shfl(pe, j + half, 64);
                unsigned sb = __shfl(pe, j + 2 + half, 64);
                unsigned sc = __shfl(pe, j + 4 + half, 64);
                unsigned sd = __shfl(pe, j + 6 + half, 64);
                unsigned g0 = nfu[(size_t)sa * 32 + dln];
                unsigned g1 = nfu[(size_t)sb * 32 + dln];
                unsigned g2 = nfu[(size_t)sc * 32 + dln];
                unsigned g3 = nfu[(size_t)sd * 32 + dln];
                m0 = pkmax(m0, pk_ord_encode(g0));
                m1 = pkmax(m1, pk_ord_encode(g1));
                m2 = pkmax(m2, pk_ord_encode(g2));
                m3 = pkmax(m3, pk_ord_encode(g3));
            }
            for (; j + 4 <= lim; j += 4) {
                unsigned sa = __shfl(pe, j + half, 64);
                unsigned sb = __shfl(pe, j + 2 + half, 64);
                unsigned g0 = nfu[(size_t)sa * 32 + dln];
                unsigned g1 = nfu[(size_t)sb * 32 + dln];
                m0 = pkmax(m0, pk_ord_encode(g0));
                m1 = pkmax(m1, pk_ord_encode(g1));
            }
            for (; j < lim; j += 2) {
                int jj = j + half;
                if (jj >= lim) jj = lim - 1;    // dup tail, convergent shfl
                unsigned g = nfu[(size_t)__shfl(pe, jj, 64) * 32 + dln];
                m0 = pkmax(m0, pk_ord_encode(g));
            }
        }
        unsigned m = pkmax(pkmax(m0, m1), pkmax(m2, m3));
        m = pkmax(m, __shfl_xor(m, 32, 64));    // cross-half merge
        if (ln < 32) {
            unsigned raw = pk_ord_decode(m);    // empty run -> NaN halves
            unsigned xr  = nfu[(size_t)n * 32 + dln];
            float v0 = __uint_as_float(raw << 16);
            float v1 = __uint_as_float(raw & 0xFFFF0000u);
            float x0 = __uint_as_float(xr << 16);
            float x1 = __uint_as_float(xr & 0xFFFF0000u);
            float r0 = v0 - x0; r0 = (r0 >= CLAMP_V) ? r0 : 0.0f;  // NaN -> 0
            float r1 = v1 - x1; r1 = (r1 >= CLAMP_V) ? r1 : 0.0f;
            __bf16 b0 = (__bf16)r0, b1 = (__bf16)r1;
            unsigned o = ((unsigned)__builtin_bit_cast(unsigned short, b1) << 16)
                       |  (unsigned)__builtin_bit_cast(unsigned short, b0);
            agg16u[(size_t)n * 32 + dln] = o;
        }
    }
}

// ---------- pass E: MFMA MLP; W from frag-order buffer ----------
__global__ __launch_bounds__(256) void node_mlp_mfma(
        const __bf16* __restrict__ nf16,
        const __bf16* __restrict__ agg16,
        float* __restrict__ out,
        const __bf16* __restrict__ wfrag,
        const float* __restrict__ bias,
        int nTiles, int nN) {
    int lane = threadIdx.x & 63;
    int quad = lane >> 4;
    int l16  = lane & 15;
    int waveGlobal = blockIdx.x * 4 + (threadIdx.x >> 6);
    int nWaves = gridDim.x * 4;

    bf16x8 bfrag[4][4];
    #pragma unroll
    for (int c = 0; c < 4; ++c)
        #pragma unroll
        for (int ks = 0; ks < 4; ++ks)
            bfrag[c][ks] = *(const bf16x8*)(wfrag + ((size_t)((ks * 4 + c) * 64 + lane)) * 8);
    float bv[4];
    #pragma unroll
    for (int c = 0; c < 4; ++c) bv[c] = bias[c * 16 + l16];

    for (int t = waveGlobal; t < nTiles; t += nWaves) {
        int n0 = t * 16;
        int rowA = n0 + l16;
        if (rowA >= nN) rowA = nN - 1;
        const __bf16* nfr = nf16  + (size_t)rowA * D;
        const __bf16* agr = agg16 + (size_t)rowA * D;

        floatx4 acc[4] = {{0,0,0,0},{0,0,0,0},{0,0,0,0},{0,0,0,0}};
        #pragma unroll
        for (int ks = 0; ks < 4; ++ks) {
            const __bf16* p = (ks < 2) ? (nfr + ks * 32 + quad * 8)
                                       : (agr + (ks - 2) * 32 + quad * 8);
            bf16x8 a = *(const bf16x8*)p;
            #pragma unroll
            for (int c = 0; c < 4; ++c)
                acc[c] = __builtin_amdgcn_mfma_f32_16x16x32_bf16(
                             a, bfrag[c][ks], acc[c], 0, 0, 0);
        }
        #pragma unroll
        for (int r = 0; r < 4; ++r) {
            int row = n0 + quad * 4 + r;
            if (row < nN) {
                #pragma unroll
                for (int c = 0; c < 4; ++c) {
                    float vv = acc[c][r] + bv[c];
                    out[(size_t)row * D + c * 16 + l16] = fmaxf(vv, 0.0f);
                }
            }
        }
    }
}

extern "C" void kernel_launch(void* const* d_in, const int* in_sizes, int n_in,
                              void* d_out, int out_size, void* d_ws, size_t ws_size,
                              hipStream_t stream) {
    const float* nf  = (const float*)d_in[0];
    const int*   src = (const int*)d_in[1];
    const int*   dst = (const int*)d_in[2];
    const float* W   = (const float*)d_in[3];
    const float* b   = (const float*)d_in[4];
    float* out = (float*)d_out;

    int nN = in_sizes[0] / D;
    int nE = in_sizes[1];
    int nbSB = (nN + SBN - 1) / SBN;            // 196

    // ws layout
    char* wsb = (char*)d_ws;
    size_t nfB  = (((size_t)nN * D * 2) + 255) & ~(size_t)255;  // 12.8 MB
    size_t pkB  = (((size_t)nE * 4)     + 255) & ~(size_t)255;  // 6.4 MB
    __bf16*   nf16   = (__bf16*)wsb;
    __bf16*   agg16  = (__bf16*)(wsb + nfB);
    unsigned* packed1 = (unsigned*)(wsb + 2 * nfB);
    unsigned* ghist  = (unsigned*)(wsb + 2 * nfB + pkB);
    unsigned* base   = (unsigned*)(wsb + 2 * nfB + pkB + 4 * MAXSB);
    unsigned* cursor = (unsigned*)(wsb + 2 * nfB + pkB + 4 * MAXSB + 4 * (MAXSB + 2));
    __bf16*   wfrag  = (__bf16*)(wsb + 2 * nfB + pkB + 4 * MAXSB + 8 * (MAXSB + 2));
    unsigned* nodestart = (unsigned*)(wsb + 2 * nfB + pkB + 4 * MAXSB
                                      + 8 * (MAXSB + 2) + 32768);
    // packed2 lives in d_out: consumed by seg_direct before the MLP writes out
    unsigned* packed2 = (unsigned*)d_out;

    hipMemsetAsync(ghist, 0, (size_t)nbSB * 4, stream);

    int n4 = nN * D / 4;                        // 1.6M
    int convBlocks = (n4 + 255) / 256;          // 6250
    int histBlocks = (nE + HCHUNK - 1) / HCHUNK;// 391
    int gridPrep = convBlocks > histBlocks ? convBlocks : histBlocks;
    prep_kernel<<<gridPrep, 256, 0, stream>>>(nf, nf16, n4, dst, ghist, nE, nbSB,
                                              W, wfrag, histBlocks, gridPrep - 1);

    scan_sb<<<1, 256, 0, stream>>>(ghist, base, cursor, nbSB);

    int nbS = (nE + SCHUNK - 1) / SCHUNK;       // 391
    sb_scatter<<<nbS, 256, 0, stream>>>(src, dst, cursor, packed1, nE, nbSB);

    sb_sort<<<nbSB, 256, 0, stream>>>(packed1, base, packed2, nodestart, nN);

    int segBlocks = (nN + 4 * NPW - 1) / (4 * NPW);   // 3125
    seg_direct<<<segBlocks, 256, 0, stream>>>(
        (const unsigned*)nf16, packed2, nodestart, (unsigned*)agg16, nN);

    int nTiles = (nN + 15) / 16;
    node_mlp_mfma<<<768, 256, 0, stream>>>(nf16, agg16, out, wfrag, b, nTiles, nN);
}